// Round 4
// baseline (2769.199 us; speedup 1.0000x reference)
//
#include <hip/hip_runtime.h>
#include <hip/hip_bf16.h>

#define ROWS 230400   // 1600 windows * 144 tokens
#define CDIM 192
#define NTOK 144
#define NWIN 1600
#define PLANE 57600   // 240*240
#define HDIM 768

typedef __attribute__((ext_vector_type(8))) short bf16x8;
typedef __attribute__((ext_vector_type(4))) float f32x4;

__device__ __forceinline__ ushort f2bf(float f) {
  union { float f; unsigned u; } v; v.f = f;
  unsigned r = v.u + 0x7FFFu + ((v.u >> 16) & 1u);
  return (ushort)(r >> 16);
}
__device__ __forceinline__ float bf2f(ushort h) {
  union { unsigned u; float f; } v; v.u = ((unsigned)h) << 16;
  return v.f;
}
__device__ __forceinline__ float gelu_f(float x) {
  return 0.5f * x * (1.f + erff(x * 0.7071067811865475f));
}

// ---------------- weight fp32 -> bf16 ----------------
struct CvtJobs {
  const float* src[8];
  ushort* dst[8];
  int n[8];
};
__global__ __launch_bounds__(256) void cvt_kernel(CvtJobs jobs) {
  int stride = gridDim.x * blockDim.x;
  int t0 = blockIdx.x * blockDim.x + threadIdx.x;
  for (int j = 0; j < 8; ++j) {
    const float* s = jobs.src[j]; ushort* d = jobs.dst[j]; int n = jobs.n[j];
    for (int e = t0; e < n; e += stride) d[e] = f2bf(s[e]);
  }
}

// ---------------- window partition + LN (opt & sar) ----------------
__global__ __launch_bounds__(256) void lnpart_kernel(
    const float* __restrict__ opt, const float* __restrict__ sar,
    const float* __restrict__ lnqw, const float* __restrict__ lnqb,
    const float* __restrict__ lnkw, const float* __restrict__ lnkb,
    ushort* __restrict__ opt_ln, ushort* __restrict__ sar_ln,
    ushort* __restrict__ opt_tok) {
  __shared__ __align__(16) ushort X[NTOK * 200];
  __shared__ float smu[NTOK], srs[NTOK];
  int win = blockIdx.x;
  int b = win / 400, rr = win % 400, nh = rr / 20, nw = rr % 20;
  size_t wbase = (size_t)b * CDIM * PLANE + (size_t)(nh * 12) * 240 + nw * 12;
  int tid = threadIdx.x;
  for (int pass = 0; pass < 2; ++pass) {
    const float* src = pass ? sar : opt;
    for (int e = tid; e < CDIM * 36; e += 256) {
      int c = e / 36, r2 = e % 36, i = r2 / 3, j0 = (r2 % 3) * 4;
      float4 v = *(const float4*)&src[wbase + (size_t)c * PLANE + i * 240 + j0];
      int tok = i * 12 + j0;
      X[(tok + 0) * 200 + c] = f2bf(v.x);
      X[(tok + 1) * 200 + c] = f2bf(v.y);
      X[(tok + 2) * 200 + c] = f2bf(v.z);
      X[(tok + 3) * 200 + c] = f2bf(v.w);
    }
    __syncthreads();
    if (tid < NTOK) {
      float s = 0.f, qs = 0.f;
      for (int c = 0; c < CDIM; ++c) { float v = bf2f(X[tid * 200 + c]); s += v; qs += v * v; }
      float mu = s * (1.f / CDIM);
      smu[tid] = mu;
      srs[tid] = rsqrtf(qs * (1.f / CDIM) - mu * mu + 1e-5f);
    }
    __syncthreads();
    const float* w = pass ? lnkw : lnqw;
    const float* bb = pass ? lnkb : lnqb;
    ushort* dst = pass ? sar_ln : opt_ln;
    for (int e = tid; e < NTOK * CDIM; e += 256) {
      int tok = e / CDIM, c = e % CDIM;
      ushort raw = X[tok * 200 + c];
      float v = bf2f(raw);
      float y = (v - smu[tok]) * srs[tok] * w[c] + bb[c];
      size_t o = (size_t)(win * NTOK + tok) * CDIM + c;
      dst[o] = f2bf(y);
      if (!pass) opt_tok[o] = raw;
    }
    __syncthreads();
  }
}

// ---------------- generic bf16 MFMA GEMM: out = epi(A @ W^T + bias) ----------------
// A: [M][K] bf16 row-major; W: [N][K] bf16 ('oi' layout, k contiguous)
enum { EPI_BF16 = 0, EPI_GELU = 1, EPI_SIG = 2, EPI_PROJ = 3 };

template <int EPI>
__global__ __launch_bounds__(256) void gemm_kernel(
    const ushort* __restrict__ A, const ushort* __restrict__ Wt,
    const float* __restrict__ bias, const float* __restrict__ bias2,
    void* __restrict__ outp, int M, int N, int K,
    const float* __restrict__ g, const ushort* __restrict__ opt_tok,
    const float* __restrict__ gamma_p) {
  __shared__ __align__(16) ushort Alds[128 * 40];  // +8 pad breaks bank aliasing
  int m0 = blockIdx.x * 128;
  int n0 = blockIdx.y * 64;
  int tid = threadIdx.x;
  int wave = tid >> 6, lane = tid & 63, ls = lane & 15, quad = lane >> 4;
  f32x4 acc[2][4] = {};
  for (int k0 = 0; k0 < K; k0 += 32) {
    for (int it = 0; it < 2; ++it) {
      int ch = tid + 256 * it;
      int r = ch >> 2, c8 = (ch & 3) * 8;
      int grow = m0 + r; if (grow > M - 1) grow = M - 1;
      *(bf16x8*)&Alds[r * 40 + c8] = *(const bf16x8*)&A[(size_t)grow * K + k0 + c8];
    }
    __syncthreads();
    int mb = wave * 32;
    bf16x8 af0 = *(const bf16x8*)&Alds[(mb + ls) * 40 + quad * 8];
    bf16x8 af1 = *(const bf16x8*)&Alds[(mb + 16 + ls) * 40 + quad * 8];
    bf16x8 bfr[4];
    for (int nf = 0; nf < 4; ++nf)
      bfr[nf] = *(const bf16x8*)&Wt[(size_t)(n0 + nf * 16 + ls) * K + k0 + quad * 8];
    for (int nf = 0; nf < 4; ++nf) {
      acc[0][nf] = __builtin_amdgcn_mfma_f32_16x16x32_bf16(af0, bfr[nf], acc[0][nf], 0, 0, 0);
      acc[1][nf] = __builtin_amdgcn_mfma_f32_16x16x32_bf16(af1, bfr[nf], acc[1][nf], 0, 0, 0);
    }
    __syncthreads();
  }
  float gam = (EPI == EPI_PROJ) ? gamma_p[0] : 0.f;
  for (int s = 0; s < 2; ++s) {
    int rowbase = m0 + wave * 32 + s * 16 + quad * 4;
    for (int nf = 0; nf < 4; ++nf) {
      int col = n0 + nf * 16 + ls;
      float bb = (col < 192) ? bias[col] : bias2[col - 192];
      for (int r = 0; r < 4; ++r) {
        int row = rowbase + r;
        if (row >= M) continue;
        float v = acc[s][nf][r] + bb;
        if (EPI == EPI_BF16) {
          ((ushort*)outp)[(size_t)row * N + col] = f2bf(v);
        } else if (EPI == EPI_GELU) {
          ((ushort*)outp)[(size_t)row * N + col] = f2bf(gelu_f(v));
        } else if (EPI == EPI_SIG) {
          ((float*)outp)[(size_t)row * N + col] = 1.f / (1.f + __expf(-v));
        } else {  // EPI_PROJ: fused = opt_tok + gamma * g * (proj)
          int win = row / NTOK;
          float gv = g[(size_t)win * CDIM + col];
          float ov = bf2f(opt_tok[(size_t)row * CDIM + col]);
          ((ushort*)outp)[(size_t)row * CDIM + col] = f2bf(ov + gam * gv * v);
        }
      }
    }
  }
}

// ---------------- per-window token-mean of sar_ln ----------------
__global__ __launch_bounds__(192) void pool_kernel(const ushort* __restrict__ sar_ln,
                                                   ushort* __restrict__ pool) {
  int win = blockIdx.x, c = threadIdx.x;
  float s = 0.f;
  size_t base = (size_t)win * NTOK * CDIM + c;
  for (int t = 0; t < NTOK; ++t) s += bf2f(sar_ln[base + (size_t)t * CDIM]);
  pool[(size_t)win * CDIM + c] = f2bf(s * (1.f / NTOK));
}

// ---------------- attention: one block per (window, head) ----------------
__global__ __launch_bounds__(256) void attn_kernel(const ushort* __restrict__ q,
                                                   const ushort* __restrict__ kv,
                                                   ushort* __restrict__ attn_out) {
  __shared__ __align__(16) ushort vT[32 * 168];     // v transposed, K zero-padded to 160
  __shared__ __align__(16) ushort P[4][16 * 168];   // per-wave P tile (A-layout source)
  int blk = blockIdx.x;
  int win = blk / 6, head = blk % 6;
  int tid = threadIdx.x, wave = tid >> 6, lane = tid & 63, ls = lane & 15, quad = lane >> 4;
  size_t qbase = (size_t)win * NTOK * CDIM + head * 32;
  size_t kbase = (size_t)win * NTOK * 384 + head * 32;
  size_t vbase = kbase + 192;
  for (int e = tid; e < NTOK * 32; e += 256) {
    int t = e >> 5, d = e & 31;
    vT[d * 168 + t] = kv[vbase + (size_t)t * 384 + d];
  }
  for (int e = tid; e < 32 * 24; e += 256) {
    int d = e / 24, j = 144 + e % 24;
    vT[d * 168 + j] = 0;
  }
  __syncthreads();
  const float scale = 0.17677669529663687f;  // 32^-0.5
  ushort* Pw = P[wave];
  f32x4 zero = {0.f, 0.f, 0.f, 0.f};
  for (int mt = wave; mt < 9; mt += 4) {
    int m0 = mt * 16;
    bf16x8 aq = *(const bf16x8*)&q[qbase + (size_t)(m0 + ls) * CDIM + quad * 8];
    f32x4 S[9];
    for (int nt = 0; nt < 9; ++nt) {
      bf16x8 bk = *(const bf16x8*)&kv[kbase + (size_t)(nt * 16 + ls) * 384 + quad * 8];
      S[nt] = __builtin_amdgcn_mfma_f32_16x16x32_bf16(aq, bk, zero, 0, 0, 0);
    }
    for (int nt = 0; nt < 9; ++nt)
      for (int r = 0; r < 4; ++r) S[nt][r] *= scale;
    // softmax per row (row = quad*4+r lives in reg r of the 16 lanes sharing `quad`)
    for (int r = 0; r < 4; ++r) {
      float mx = -1e30f;
      for (int nt = 0; nt < 9; ++nt) mx = fmaxf(mx, S[nt][r]);
      for (int o = 1; o < 16; o <<= 1) mx = fmaxf(mx, __shfl_xor(mx, o));
      float sm = 0.f;
      for (int nt = 0; nt < 9; ++nt) { float e = __expf(S[nt][r] - mx); S[nt][r] = e; sm += e; }
      for (int o = 1; o < 16; o <<= 1) sm += __shfl_xor(sm, o);
      float inv = 1.f / sm;
      for (int nt = 0; nt < 9; ++nt)
        Pw[(quad * 4 + r) * 168 + nt * 16 + ls] = f2bf(S[nt][r] * inv);
    }
    for (int e = lane; e < 16 * 24; e += 64) {  // zero K-pad cols 144..167
      int r = e / 24, j = 144 + e % 24;
      Pw[r * 168 + j] = 0;
    }
    f32x4 O[2] = {};
    for (int ks = 0; ks < 5; ++ks) {
      bf16x8 ap = *(const bf16x8*)&Pw[ls * 168 + ks * 32 + quad * 8];
      for (int dt = 0; dt < 2; ++dt) {
        bf16x8 bv = *(const bf16x8*)&vT[(dt * 16 + ls) * 168 + ks * 32 + quad * 8];
        O[dt] = __builtin_amdgcn_mfma_f32_16x16x32_bf16(ap, bv, O[dt], 0, 0, 0);
      }
    }
    for (int dt = 0; dt < 2; ++dt)
      for (int r = 0; r < 4; ++r)
        attn_out[(size_t)(win * NTOK + m0 + quad * 4 + r) * CDIM + head * 32 + dt * 16 + ls] =
            f2bf(O[dt][r]);
  }
}

// ---------------- row LayerNorm (one wave per token) ----------------
__global__ __launch_bounds__(256) void lno_kernel(const ushort* __restrict__ x,
                                                  const float* __restrict__ w,
                                                  const float* __restrict__ b,
                                                  ushort* __restrict__ out) {
  int row = blockIdx.x * 4 + (threadIdx.x >> 6);
  int lane = threadIdx.x & 63;
  const ushort* xr = x + (size_t)row * CDIM;
  float v[3], s = 0.f, qs = 0.f;
  for (int i = 0; i < 3; ++i) { v[i] = bf2f(xr[lane + 64 * i]); s += v[i]; qs += v[i] * v[i]; }
  for (int o = 1; o < 64; o <<= 1) { s += __shfl_xor(s, o); qs += __shfl_xor(qs, o); }
  float mu = s * (1.f / CDIM);
  float rs = rsqrtf(qs * (1.f / CDIM) - mu * mu + 1e-5f);
  ushort* orow = out + (size_t)row * CDIM;
  for (int i = 0; i < 3; ++i) {
    int c = lane + 64 * i;
    orow[c] = f2bf((v[i] - mu) * rs * w[c] + b[c]);
  }
}

// ---------------- fused MLP: y = fused + gelu(h@w1^T+b1)@w2^T + b2 ----------------
// Barrier-free R0 structure: BM=64, each wave owns 16 rows x all 192 cols.
// Persistent state: afrag[6]=24 + acc[12]=48 = 72 VGPRs -> needs the 128-VGPR
// tier. R1/R2 lesson: at 9.2KB LDS the backend targets 8 waves/EU, clamps to
// 64 VGPRs and spills (waves_per_eu attribute was ignored). The reliable lever
// is LDS itself: 36864 B > 32768 B caps residency at 4 blocks/CU -> max
// 4 waves/EU -> the allocator gets the full 128-VGPR budget. Only the first
// 64*72 shorts of Ts are used; the tail exists purely as the occupancy lever.
// Zero __syncthreads (Ts rows are wave-private; same-wave ds_write->ds_read
// ordering is handled by compiler-inserted lgkmcnt waits).
__global__ __launch_bounds__(256) void mlp_kernel(
    const ushort* __restrict__ h, const ushort* __restrict__ fused,
    const ushort* __restrict__ w1b, const float* __restrict__ b1,
    const ushort* __restrict__ w2b, const float* __restrict__ b2,
    ushort* __restrict__ y) {
  __shared__ __align__(16) ushort Ts[18432];  // 36864 B; used: 64*72 = 9216 shorts
  int m0 = blockIdx.x * 64;
  int tid = threadIdx.x, wave = tid >> 6, lane = tid & 63, ls = lane & 15, quad = lane >> 4;
  int wrow = wave * 16;
  // A fragments for this wave's 16 rows, all of K=192: 6 x bf16x8 = 24 VGPRs.
  bf16x8 afrag[6];
#pragma unroll
  for (int ks = 0; ks < 6; ++ks)
    afrag[ks] = *(const bf16x8*)&h[(size_t)(m0 + wrow + ls) * CDIM + ks * 32 + quad * 8];
  f32x4 acc[12] = {};
  for (int hc = 0; hc < HDIM; hc += 64) {
    f32x4 t[4] = {};
#pragma unroll
    for (int ks = 0; ks < 6; ++ks) {
#pragma unroll
      for (int nf = 0; nf < 4; ++nf) {
        bf16x8 bw = *(const bf16x8*)&w1b[(size_t)(hc + nf * 16 + ls) * CDIM + ks * 32 + quad * 8];
        t[nf] = __builtin_amdgcn_mfma_f32_16x16x32_bf16(afrag[ks], bw, t[nf], 0, 0, 0);
      }
    }
#pragma unroll
    for (int nf = 0; nf < 4; ++nf) {
      float bb = b1[hc + nf * 16 + ls];
#pragma unroll
      for (int r = 0; r < 4; ++r) {
        float v = gelu_f(t[nf][r] + bb);
        Ts[(wrow + quad * 4 + r) * 72 + nf * 16 + ls] = f2bf(v);
      }
    }
#pragma unroll
    for (int ks = 0; ks < 2; ++ks) {
      bf16x8 ap = *(const bf16x8*)&Ts[(wrow + ls) * 72 + ks * 32 + quad * 8];
#pragma unroll
      for (int nf = 0; nf < 12; ++nf) {
        bf16x8 bw = *(const bf16x8*)&w2b[(size_t)(nf * 16 + ls) * HDIM + hc + ks * 32 + quad * 8];
        acc[nf] = __builtin_amdgcn_mfma_f32_16x16x32_bf16(ap, bw, acc[nf], 0, 0, 0);
      }
    }
  }
#pragma unroll
  for (int nf = 0; nf < 12; ++nf) {
    float bb = b2[nf * 16 + ls];
#pragma unroll
    for (int r = 0; r < 4; ++r) {
      size_t idx = (size_t)(m0 + wrow + quad * 4 + r) * CDIM + nf * 16 + ls;
      y[idx] = f2bf(bf2f(fused[idx]) + acc[nf][r] + bb);
    }
  }
}

// ---------------- window reverse -> [B,C,H,W] fp32 ----------------
__global__ __launch_bounds__(256) void unpart_kernel(const ushort* __restrict__ y,
                                                     float* __restrict__ out) {
  __shared__ __align__(16) ushort X[NTOK * 200];
  int win = blockIdx.x;
  int b = win / 400, rr = win % 400, nh = rr / 20, nw = rr % 20;
  size_t wbase = (size_t)b * CDIM * PLANE + (size_t)(nh * 12) * 240 + nw * 12;
  int tid = threadIdx.x;
  for (int e = tid; e < NTOK * 24; e += 256) {
    int tok = e / 24, c8 = (e % 24) * 8;
    *(bf16x8*)&X[tok * 200 + c8] = *(const bf16x8*)&y[(size_t)(win * NTOK + tok) * CDIM + c8];
  }
  __syncthreads();
  for (int e = tid; e < CDIM * 36; e += 256) {
    int c = e / 36, r2 = e % 36, i = r2 / 3, j0 = (r2 % 3) * 4;
    int tok = i * 12 + j0;
    float4 v;
    v.x = bf2f(X[(tok + 0) * 200 + c]);
    v.y = bf2f(X[(tok + 1) * 200 + c]);
    v.z = bf2f(X[(tok + 2) * 200 + c]);
    v.w = bf2f(X[(tok + 3) * 200 + c]);
    *(float4*)&out[wbase + (size_t)c * PLANE + i * 240 + j0] = v;
  }
}

extern "C" void kernel_launch(void* const* d_in, const int* in_sizes, int n_in,
                              void* d_out, int out_size, void* d_ws, size_t ws_size,
                              hipStream_t stream) {
  const float* opt   = (const float*)d_in[0];
  const float* sar   = (const float*)d_in[1];
  const float* lnqw  = (const float*)d_in[2];
  const float* lnqb  = (const float*)d_in[3];
  const float* lnkw  = (const float*)d_in[4];
  const float* lnkb  = (const float*)d_in[5];
  const float* wq    = (const float*)d_in[6];
  const float* bq    = (const float*)d_in[7];
  const float* wk    = (const float*)d_in[8];
  const float* bk    = (const float*)d_in[9];
  const float* wv    = (const float*)d_in[10];
  const float* bv    = (const float*)d_in[11];
  const float* wp    = (const float*)d_in[12];
  const float* bp    = (const float*)d_in[13];
  const float* gw1   = (const float*)d_in[14];
  const float* gb1   = (const float*)d_in[15];
  const float* gw2   = (const float*)d_in[16];
  const float* gb2   = (const float*)d_in[17];
  const float* gamma = (const float*)d_in[18];
  const float* lnow  = (const float*)d_in[19];
  const float* lnob  = (const float*)d_in[20];
  const float* w1    = (const float*)d_in[21];
  const float* b1    = (const float*)d_in[22];
  const float* w2    = (const float*)d_in[23];
  const float* b2    = (const float*)d_in[24];

  char* ws = (char*)d_ws;
  size_t off = 0;
  auto take = [&](size_t bytes) -> char* {
    char* p = ws + off;
    off += (bytes + 255) & ~(size_t)255;
    return p;
  };
  const size_t big = (size_t)ROWS * CDIM * 2;  // 88.5 MB
  ushort* opt_ln  = (ushort*)take(big);                 // -> reused as h
  ushort* sar_ln  = (ushort*)take(big);                 // -> attn_out -> y
  ushort* opt_tok = (ushort*)take(big);
  ushort* qb      = (ushort*)take(big);                 // -> fused
  ushort* kv      = (ushort*)take((size_t)ROWS * 384 * 2);
  ushort* wq_bf   = (ushort*)take(CDIM * CDIM * 2);
  ushort* wkv_bf  = (ushort*)take(2 * CDIM * CDIM * 2);
  ushort* wp_bf   = (ushort*)take(CDIM * CDIM * 2);
  ushort* w1_bf   = (ushort*)take((size_t)HDIM * CDIM * 2);
  ushort* w2_bf   = (ushort*)take((size_t)CDIM * HDIM * 2);
  ushort* gw1_bf  = (ushort*)take(CDIM * CDIM * 2);
  ushort* gw2_bf  = (ushort*)take(CDIM * CDIM * 2);
  ushort* pool_bf = (ushort*)take(NWIN * CDIM * 2);
  ushort* g1_bf   = (ushort*)take(NWIN * CDIM * 2);
  float*  g_f     = (float*)take(NWIN * CDIM * 4);
  ushort* h        = opt_ln;
  ushort* attn_out = sar_ln;
  ushort* fused    = qb;
  ushort* yb       = sar_ln;

  CvtJobs jobs;
  jobs.src[0] = wq;  jobs.dst[0] = wq_bf;               jobs.n[0] = CDIM * CDIM;
  jobs.src[1] = wk;  jobs.dst[1] = wkv_bf;              jobs.n[1] = CDIM * CDIM;
  jobs.src[2] = wv;  jobs.dst[2] = wkv_bf + CDIM * CDIM; jobs.n[2] = CDIM * CDIM;
  jobs.src[3] = wp;  jobs.dst[3] = wp_bf;               jobs.n[3] = CDIM * CDIM;
  jobs.src[4] = w1;  jobs.dst[4] = w1_bf;               jobs.n[4] = HDIM * CDIM;
  jobs.src[5] = w2;  jobs.dst[5] = w2_bf;               jobs.n[5] = CDIM * HDIM;
  jobs.src[6] = gw1; jobs.dst[6] = gw1_bf;              jobs.n[6] = CDIM * CDIM;
  jobs.src[7] = gw2; jobs.dst[7] = gw2_bf;              jobs.n[7] = CDIM * CDIM;
  cvt_kernel<<<dim3(128), dim3(256), 0, stream>>>(jobs);

  lnpart_kernel<<<dim3(NWIN), dim3(256), 0, stream>>>(
      opt, sar, lnqw, lnqb, lnkw, lnkb, opt_ln, sar_ln, opt_tok);

  gemm_kernel<EPI_BF16><<<dim3(1800, 3), dim3(256), 0, stream>>>(
      opt_ln, wq_bf, bq, bq, (void*)qb, ROWS, CDIM, CDIM, nullptr, nullptr, nullptr);
  gemm_kernel<EPI_BF16><<<dim3(1800, 6), dim3(256), 0, stream>>>(
      sar_ln, wkv_bf, bk, bv, (void*)kv, ROWS, 384, CDIM, nullptr, nullptr, nullptr);

  pool_kernel<<<dim3(NWIN), dim3(192), 0, stream>>>(sar_ln, pool_bf);
  gemm_kernel<EPI_GELU><<<dim3(13, 3), dim3(256), 0, stream>>>(
      pool_bf, gw1_bf, gb1, gb1, (void*)g1_bf, NWIN, CDIM, CDIM, nullptr, nullptr, nullptr);
  gemm_kernel<EPI_SIG><<<dim3(13, 3), dim3(256), 0, stream>>>(
      g1_bf, gw2_bf, gb2, gb2, (void*)g_f, NWIN, CDIM, CDIM, nullptr, nullptr, nullptr);

  attn_kernel<<<dim3(NWIN * 6), dim3(256), 0, stream>>>(qb, kv, attn_out);

  gemm_kernel<EPI_PROJ><<<dim3(1800, 3), dim3(256), 0, stream>>>(
      attn_out, wp_bf, bp, bp, (void*)fused, ROWS, CDIM, CDIM, g_f, opt_tok, gamma);

  lno_kernel<<<dim3(ROWS / 4), dim3(256), 0, stream>>>(fused, lnow, lnob, h);

  mlp_kernel<<<dim3(ROWS / 64), dim3(256), 0, stream>>>(h, fused, w1_bf, b1, w2_bf, b2, yb);

  unpart_kernel<<<dim3(NWIN), dim3(256), 0, stream>>>(yb, (float*)d_out);
}

// Round 5
// 1965.049 us; speedup vs baseline: 1.4092x; 1.4092x over previous
//
#include <hip/hip_runtime.h>
#include <hip/hip_bf16.h>

#define ROWS 230400   // 1600 windows * 144 tokens
#define CDIM 192
#define NTOK 144
#define NWIN 1600
#define PLANE 57600   // 240*240
#define HDIM 768

typedef __attribute__((ext_vector_type(8))) short bf16x8;
typedef __attribute__((ext_vector_type(4))) float f32x4;

__device__ __forceinline__ ushort f2bf(float f) {
  union { float f; unsigned u; } v; v.f = f;
  unsigned r = v.u + 0x7FFFu + ((v.u >> 16) & 1u);
  return (ushort)(r >> 16);
}
__device__ __forceinline__ float bf2f(ushort h) {
  union { unsigned u; float f; } v; v.u = ((unsigned)h) << 16;
  return v.f;
}
__device__ __forceinline__ float gelu_f(float x) {
  return 0.5f * x * (1.f + erff(x * 0.7071067811865475f));
}

// ---------------- weight fp32 -> bf16 ----------------
struct CvtJobs {
  const float* src[8];
  ushort* dst[8];
  int n[8];
};
__global__ __launch_bounds__(256) void cvt_kernel(CvtJobs jobs) {
  int stride = gridDim.x * blockDim.x;
  int t0 = blockIdx.x * blockDim.x + threadIdx.x;
  for (int j = 0; j < 8; ++j) {
    const float* s = jobs.src[j]; ushort* d = jobs.dst[j]; int n = jobs.n[j];
    for (int e = t0; e < n; e += stride) d[e] = f2bf(s[e]);
  }
}

// ---------------- window partition + LN (opt & sar) ----------------
__global__ __launch_bounds__(256) void lnpart_kernel(
    const float* __restrict__ opt, const float* __restrict__ sar,
    const float* __restrict__ lnqw, const float* __restrict__ lnqb,
    const float* __restrict__ lnkw, const float* __restrict__ lnkb,
    ushort* __restrict__ opt_ln, ushort* __restrict__ sar_ln,
    ushort* __restrict__ opt_tok) {
  __shared__ __align__(16) ushort X[NTOK * 200];
  __shared__ float smu[NTOK], srs[NTOK];
  int win = blockIdx.x;
  int b = win / 400, rr = win % 400, nh = rr / 20, nw = rr % 20;
  size_t wbase = (size_t)b * CDIM * PLANE + (size_t)(nh * 12) * 240 + nw * 12;
  int tid = threadIdx.x;
  for (int pass = 0; pass < 2; ++pass) {
    const float* src = pass ? sar : opt;
    for (int e = tid; e < CDIM * 36; e += 256) {
      int c = e / 36, r2 = e % 36, i = r2 / 3, j0 = (r2 % 3) * 4;
      float4 v = *(const float4*)&src[wbase + (size_t)c * PLANE + i * 240 + j0];
      int tok = i * 12 + j0;
      X[(tok + 0) * 200 + c] = f2bf(v.x);
      X[(tok + 1) * 200 + c] = f2bf(v.y);
      X[(tok + 2) * 200 + c] = f2bf(v.z);
      X[(tok + 3) * 200 + c] = f2bf(v.w);
    }
    __syncthreads();
    if (tid < NTOK) {
      float s = 0.f, qs = 0.f;
      for (int c = 0; c < CDIM; ++c) { float v = bf2f(X[tid * 200 + c]); s += v; qs += v * v; }
      float mu = s * (1.f / CDIM);
      smu[tid] = mu;
      srs[tid] = rsqrtf(qs * (1.f / CDIM) - mu * mu + 1e-5f);
    }
    __syncthreads();
    const float* w = pass ? lnkw : lnqw;
    const float* bb = pass ? lnkb : lnqb;
    ushort* dst = pass ? sar_ln : opt_ln;
    for (int e = tid; e < NTOK * CDIM; e += 256) {
      int tok = e / CDIM, c = e % CDIM;
      ushort raw = X[tok * 200 + c];
      float v = bf2f(raw);
      float y = (v - smu[tok]) * srs[tok] * w[c] + bb[c];
      size_t o = (size_t)(win * NTOK + tok) * CDIM + c;
      dst[o] = f2bf(y);
      if (!pass) opt_tok[o] = raw;
    }
    __syncthreads();
  }
}

// ---------------- generic bf16 MFMA GEMM: out = epi(A @ W^T + bias) ----------------
// A: [M][K] bf16 row-major; W: [N][K] bf16 ('oi' layout, k contiguous)
enum { EPI_BF16 = 0, EPI_GELU = 1, EPI_SIG = 2, EPI_PROJ = 3 };

template <int EPI>
__global__ __launch_bounds__(256) void gemm_kernel(
    const ushort* __restrict__ A, const ushort* __restrict__ Wt,
    const float* __restrict__ bias, const float* __restrict__ bias2,
    void* __restrict__ outp, int M, int N, int K,
    const float* __restrict__ g, const ushort* __restrict__ opt_tok,
    const float* __restrict__ gamma_p) {
  __shared__ __align__(16) ushort Alds[128 * 40];  // +8 pad breaks bank aliasing
  int m0 = blockIdx.x * 128;
  int n0 = blockIdx.y * 64;
  int tid = threadIdx.x;
  int wave = tid >> 6, lane = tid & 63, ls = lane & 15, quad = lane >> 4;
  f32x4 acc[2][4] = {};
  for (int k0 = 0; k0 < K; k0 += 32) {
    for (int it = 0; it < 2; ++it) {
      int ch = tid + 256 * it;
      int r = ch >> 2, c8 = (ch & 3) * 8;
      int grow = m0 + r; if (grow > M - 1) grow = M - 1;
      *(bf16x8*)&Alds[r * 40 + c8] = *(const bf16x8*)&A[(size_t)grow * K + k0 + c8];
    }
    __syncthreads();
    int mb = wave * 32;
    bf16x8 af0 = *(const bf16x8*)&Alds[(mb + ls) * 40 + quad * 8];
    bf16x8 af1 = *(const bf16x8*)&Alds[(mb + 16 + ls) * 40 + quad * 8];
    bf16x8 bfr[4];
    for (int nf = 0; nf < 4; ++nf)
      bfr[nf] = *(const bf16x8*)&Wt[(size_t)(n0 + nf * 16 + ls) * K + k0 + quad * 8];
    for (int nf = 0; nf < 4; ++nf) {
      acc[0][nf] = __builtin_amdgcn_mfma_f32_16x16x32_bf16(af0, bfr[nf], acc[0][nf], 0, 0, 0);
      acc[1][nf] = __builtin_amdgcn_mfma_f32_16x16x32_bf16(af1, bfr[nf], acc[1][nf], 0, 0, 0);
    }
    __syncthreads();
  }
  float gam = (EPI == EPI_PROJ) ? gamma_p[0] : 0.f;
  for (int s = 0; s < 2; ++s) {
    int rowbase = m0 + wave * 32 + s * 16 + quad * 4;
    for (int nf = 0; nf < 4; ++nf) {
      int col = n0 + nf * 16 + ls;
      float bb = (col < 192) ? bias[col] : bias2[col - 192];
      for (int r = 0; r < 4; ++r) {
        int row = rowbase + r;
        if (row >= M) continue;
        float v = acc[s][nf][r] + bb;
        if (EPI == EPI_BF16) {
          ((ushort*)outp)[(size_t)row * N + col] = f2bf(v);
        } else if (EPI == EPI_GELU) {
          ((ushort*)outp)[(size_t)row * N + col] = f2bf(gelu_f(v));
        } else if (EPI == EPI_SIG) {
          ((float*)outp)[(size_t)row * N + col] = 1.f / (1.f + __expf(-v));
        } else {  // EPI_PROJ: fused = opt_tok + gamma * g * (proj)
          int win = row / NTOK;
          float gv = g[(size_t)win * CDIM + col];
          float ov = bf2f(opt_tok[(size_t)row * CDIM + col]);
          ((ushort*)outp)[(size_t)row * CDIM + col] = f2bf(ov + gam * gv * v);
        }
      }
    }
  }
}

// ---------------- per-window token-mean of sar_ln ----------------
__global__ __launch_bounds__(192) void pool_kernel(const ushort* __restrict__ sar_ln,
                                                   ushort* __restrict__ pool) {
  int win = blockIdx.x, c = threadIdx.x;
  float s = 0.f;
  size_t base = (size_t)win * NTOK * CDIM + c;
  for (int t = 0; t < NTOK; ++t) s += bf2f(sar_ln[base + (size_t)t * CDIM]);
  pool[(size_t)win * CDIM + c] = f2bf(s * (1.f / NTOK));
}

// ---------------- attention: one block per (window, head) ----------------
__global__ __launch_bounds__(256) void attn_kernel(const ushort* __restrict__ q,
                                                   const ushort* __restrict__ kv,
                                                   ushort* __restrict__ attn_out) {
  __shared__ __align__(16) ushort vT[32 * 168];     // v transposed, K zero-padded to 160
  __shared__ __align__(16) ushort P[4][16 * 168];   // per-wave P tile (A-layout source)
  int blk = blockIdx.x;
  int win = blk / 6, head = blk % 6;
  int tid = threadIdx.x, wave = tid >> 6, lane = tid & 63, ls = lane & 15, quad = lane >> 4;
  size_t qbase = (size_t)win * NTOK * CDIM + head * 32;
  size_t kbase = (size_t)win * NTOK * 384 + head * 32;
  size_t vbase = kbase + 192;
  for (int e = tid; e < NTOK * 32; e += 256) {
    int t = e >> 5, d = e & 31;
    vT[d * 168 + t] = kv[vbase + (size_t)t * 384 + d];
  }
  for (int e = tid; e < 32 * 24; e += 256) {
    int d = e / 24, j = 144 + e % 24;
    vT[d * 168 + j] = 0;
  }
  __syncthreads();
  const float scale = 0.17677669529663687f;  // 32^-0.5
  ushort* Pw = P[wave];
  f32x4 zero = {0.f, 0.f, 0.f, 0.f};
  for (int mt = wave; mt < 9; mt += 4) {
    int m0 = mt * 16;
    bf16x8 aq = *(const bf16x8*)&q[qbase + (size_t)(m0 + ls) * CDIM + quad * 8];
    f32x4 S[9];
    for (int nt = 0; nt < 9; ++nt) {
      bf16x8 bk = *(const bf16x8*)&kv[kbase + (size_t)(nt * 16 + ls) * 384 + quad * 8];
      S[nt] = __builtin_amdgcn_mfma_f32_16x16x32_bf16(aq, bk, zero, 0, 0, 0);
    }
    for (int nt = 0; nt < 9; ++nt)
      for (int r = 0; r < 4; ++r) S[nt][r] *= scale;
    // softmax per row (row = quad*4+r lives in reg r of the 16 lanes sharing `quad`)
    for (int r = 0; r < 4; ++r) {
      float mx = -1e30f;
      for (int nt = 0; nt < 9; ++nt) mx = fmaxf(mx, S[nt][r]);
      for (int o = 1; o < 16; o <<= 1) mx = fmaxf(mx, __shfl_xor(mx, o));
      float sm = 0.f;
      for (int nt = 0; nt < 9; ++nt) { float e = __expf(S[nt][r] - mx); S[nt][r] = e; sm += e; }
      for (int o = 1; o < 16; o <<= 1) sm += __shfl_xor(sm, o);
      float inv = 1.f / sm;
      for (int nt = 0; nt < 9; ++nt)
        Pw[(quad * 4 + r) * 168 + nt * 16 + ls] = f2bf(S[nt][r] * inv);
    }
    for (int e = lane; e < 16 * 24; e += 64) {  // zero K-pad cols 144..167
      int r = e / 24, j = 144 + e % 24;
      Pw[r * 168 + j] = 0;
    }
    f32x4 O[2] = {};
    for (int ks = 0; ks < 5; ++ks) {
      bf16x8 ap = *(const bf16x8*)&Pw[ls * 168 + ks * 32 + quad * 8];
      for (int dt = 0; dt < 2; ++dt) {
        bf16x8 bv = *(const bf16x8*)&vT[(dt * 16 + ls) * 168 + ks * 32 + quad * 8];
        O[dt] = __builtin_amdgcn_mfma_f32_16x16x32_bf16(ap, bv, O[dt], 0, 0, 0);
      }
    }
    for (int dt = 0; dt < 2; ++dt)
      for (int r = 0; r < 4; ++r)
        attn_out[(size_t)(win * NTOK + m0 + quad * 4 + r) * CDIM + head * 32 + dt * 16 + ls] =
            f2bf(O[dt][r]);
  }
}

// ---------------- row LayerNorm (one wave per token) ----------------
__global__ __launch_bounds__(256) void lno_kernel(const ushort* __restrict__ x,
                                                  const float* __restrict__ w,
                                                  const float* __restrict__ b,
                                                  ushort* __restrict__ out) {
  int row = blockIdx.x * 4 + (threadIdx.x >> 6);
  int lane = threadIdx.x & 63;
  const ushort* xr = x + (size_t)row * CDIM;
  float v[3], s = 0.f, qs = 0.f;
  for (int i = 0; i < 3; ++i) { v[i] = bf2f(xr[lane + 64 * i]); s += v[i]; qs += v[i] * v[i]; }
  for (int o = 1; o < 64; o <<= 1) { s += __shfl_xor(s, o); qs += __shfl_xor(qs, o); }
  float mu = s * (1.f / CDIM);
  float rs = rsqrtf(qs * (1.f / CDIM) - mu * mu + 1e-5f);
  ushort* orow = out + (size_t)row * CDIM;
  for (int i = 0; i < 3; ++i) {
    int c = lane + 64 * i;
    orow[c] = f2bf((v[i] - mu) * rs * w[c] + b[c]);
  }
}

// ---------------- fused MLP: y = fused + gelu(h@w1^T+b1)@w2^T + b2 ----------------
// R4 post-mortem: no-spill barrier-free version was STILL 1205 us because the
// critical path is the per-wave L2 weight-fragment load -> MFMA chain with only
// 1x reuse. Fix: stage per-32-hidden-chunk weight slices in LDS, shared by all
// 4 waves (4x less L2 traffic, ds_read latency instead of L2 latency).
// LDS = W1s 12.8K + W2s 15.4K + Ts 5.1K = 33.3K -> 4 blocks/CU (16 waves/CU)
// and the backend's LDS-implied occupancy bound (4 waves/EU) grants the full
// 128-VGPR budget (R4-validated inference). Persistent regs: afrag 24 + acc 48
// = 72 -> no spill. Two barriers per chunk; 4 independent blocks/CU hide them.
__global__ __launch_bounds__(256) void mlp_kernel(
    const ushort* __restrict__ h, const ushort* __restrict__ fused,
    const ushort* __restrict__ w1b, const float* __restrict__ b1,
    const ushort* __restrict__ w2b, const float* __restrict__ b2,
    ushort* __restrict__ y) {
  __shared__ __align__(16) ushort W1s[32 * 200];  // w1 chunk [32 hid][192 k], pad->200
  __shared__ __align__(16) ushort W2s[192 * 40];  // w2 chunk [192 out][32 k], pad->40
  __shared__ __align__(16) ushort Ts[64 * 40];    // gelu(t) [64 rows][32 k], pad->40
  int m0 = blockIdx.x * 64;
  int tid = threadIdx.x, wave = tid >> 6, lane = tid & 63, ls = lane & 15, quad = lane >> 4;
  int wrow = wave * 16;
  // A fragments for this wave's 16 rows, all of K=192: 6 x bf16x8 = 24 VGPRs.
  bf16x8 afrag[6];
#pragma unroll
  for (int ks = 0; ks < 6; ++ks)
    afrag[ks] = *(const bf16x8*)&h[(size_t)(m0 + wrow + ls) * CDIM + ks * 32 + quad * 8];
  f32x4 acc[12] = {};
  for (int hc = 0; hc < HDIM; hc += 32) {
    __syncthreads();  // all waves done reading previous chunk's W1s/W2s
    // stage w1 rows [hc, hc+32): 32*24 = 768 vec8, 3 per thread
    {
      int ch = tid;
#pragma unroll
      for (int it = 0; it < 3; ++it, ch += 256) {
        int r = ch / 24, c8 = (ch % 24) * 8;
        *(bf16x8*)&W1s[r * 200 + c8] = *(const bf16x8*)&w1b[(size_t)(hc + r) * CDIM + c8];
      }
      // stage w2 k-cols [hc, hc+32) for all 192 out rows: 192*4 = 768 vec8
      int ch2 = tid;
#pragma unroll
      for (int it = 0; it < 3; ++it, ch2 += 256) {
        int r = ch2 / 4, c8 = (ch2 % 4) * 8;
        *(bf16x8*)&W2s[r * 40 + c8] = *(const bf16x8*)&w2b[(size_t)r * HDIM + hc + c8];
      }
    }
    __syncthreads();  // chunk staged
    // GEMM1: 16 rows x 32 hidden cols, K=192
    f32x4 t[2] = {};
#pragma unroll
    for (int ks = 0; ks < 6; ++ks) {
#pragma unroll
      for (int nf = 0; nf < 2; ++nf) {
        bf16x8 bw = *(const bf16x8*)&W1s[(nf * 16 + ls) * 200 + ks * 32 + quad * 8];
        t[nf] = __builtin_amdgcn_mfma_f32_16x16x32_bf16(afrag[ks], bw, t[nf], 0, 0, 0);
      }
    }
    // bias + gelu -> Ts (wave-private rows; same-wave write->read via lgkmcnt)
#pragma unroll
    for (int nf = 0; nf < 2; ++nf) {
      float bb = b1[hc + nf * 16 + ls];
#pragma unroll
      for (int r = 0; r < 4; ++r) {
        float v = gelu_f(t[nf][r] + bb);
        Ts[(wrow + quad * 4 + r) * 40 + nf * 16 + ls] = f2bf(v);
      }
    }
    // GEMM2: 16 rows x 192 out cols, K=32 (this chunk), accumulate
    bf16x8 ap = *(const bf16x8*)&Ts[(wrow + ls) * 40 + quad * 8];
#pragma unroll
    for (int nf = 0; nf < 12; ++nf) {
      bf16x8 bw = *(const bf16x8*)&W2s[(nf * 16 + ls) * 40 + quad * 8];
      acc[nf] = __builtin_amdgcn_mfma_f32_16x16x32_bf16(ap, bw, acc[nf], 0, 0, 0);
    }
  }
#pragma unroll
  for (int nf = 0; nf < 12; ++nf) {
    float bb = b2[nf * 16 + ls];
#pragma unroll
    for (int r = 0; r < 4; ++r) {
      size_t idx = (size_t)(m0 + wrow + quad * 4 + r) * CDIM + nf * 16 + ls;
      y[idx] = f2bf(bf2f(fused[idx]) + acc[nf][r] + bb);
    }
  }
}

// ---------------- window reverse -> [B,C,H,W] fp32 ----------------
__global__ __launch_bounds__(256) void unpart_kernel(const ushort* __restrict__ y,
                                                     float* __restrict__ out) {
  __shared__ __align__(16) ushort X[NTOK * 200];
  int win = blockIdx.x;
  int b = win / 400, rr = win % 400, nh = rr / 20, nw = rr % 20;
  size_t wbase = (size_t)b * CDIM * PLANE + (size_t)(nh * 12) * 240 + nw * 12;
  int tid = threadIdx.x;
  for (int e = tid; e < NTOK * 24; e += 256) {
    int tok = e / 24, c8 = (e % 24) * 8;
    *(bf16x8*)&X[tok * 200 + c8] = *(const bf16x8*)&y[(size_t)(win * NTOK + tok) * CDIM + c8];
  }
  __syncthreads();
  for (int e = tid; e < CDIM * 36; e += 256) {
    int c = e / 36, r2 = e % 36, i = r2 / 3, j0 = (r2 % 3) * 4;
    int tok = i * 12 + j0;
    float4 v;
    v.x = bf2f(X[(tok + 0) * 200 + c]);
    v.y = bf2f(X[(tok + 1) * 200 + c]);
    v.z = bf2f(X[(tok + 2) * 200 + c]);
    v.w = bf2f(X[(tok + 3) * 200 + c]);
    *(float4*)&out[wbase + (size_t)c * PLANE + i * 240 + j0] = v;
  }
}

extern "C" void kernel_launch(void* const* d_in, const int* in_sizes, int n_in,
                              void* d_out, int out_size, void* d_ws, size_t ws_size,
                              hipStream_t stream) {
  const float* opt   = (const float*)d_in[0];
  const float* sar   = (const float*)d_in[1];
  const float* lnqw  = (const float*)d_in[2];
  const float* lnqb  = (const float*)d_in[3];
  const float* lnkw  = (const float*)d_in[4];
  const float* lnkb  = (const float*)d_in[5];
  const float* wq    = (const float*)d_in[6];
  const float* bq    = (const float*)d_in[7];
  const float* wk    = (const float*)d_in[8];
  const float* bk    = (const float*)d_in[9];
  const float* wv    = (const float*)d_in[10];
  const float* bv    = (const float*)d_in[11];
  const float* wp    = (const float*)d_in[12];
  const float* bp    = (const float*)d_in[13];
  const float* gw1   = (const float*)d_in[14];
  const float* gb1   = (const float*)d_in[15];
  const float* gw2   = (const float*)d_in[16];
  const float* gb2   = (const float*)d_in[17];
  const float* gamma = (const float*)d_in[18];
  const float* lnow  = (const float*)d_in[19];
  const float* lnob  = (const float*)d_in[20];
  const float* w1    = (const float*)d_in[21];
  const float* b1    = (const float*)d_in[22];
  const float* w2    = (const float*)d_in[23];
  const float* b2    = (const float*)d_in[24];

  char* ws = (char*)d_ws;
  size_t off = 0;
  auto take = [&](size_t bytes) -> char* {
    char* p = ws + off;
    off += (bytes + 255) & ~(size_t)255;
    return p;
  };
  const size_t big = (size_t)ROWS * CDIM * 2;  // 88.5 MB
  ushort* opt_ln  = (ushort*)take(big);                 // -> reused as h
  ushort* sar_ln  = (ushort*)take(big);                 // -> attn_out -> y
  ushort* opt_tok = (ushort*)take(big);
  ushort* qb      = (ushort*)take(big);                 // -> fused
  ushort* kv      = (ushort*)take((size_t)ROWS * 384 * 2);
  ushort* wq_bf   = (ushort*)take(CDIM * CDIM * 2);
  ushort* wkv_bf  = (ushort*)take(2 * CDIM * CDIM * 2);
  ushort* wp_bf   = (ushort*)take(CDIM * CDIM * 2);
  ushort* w1_bf   = (ushort*)take((size_t)HDIM * CDIM * 2);
  ushort* w2_bf   = (ushort*)take((size_t)CDIM * HDIM * 2);
  ushort* gw1_bf  = (ushort*)take(CDIM * CDIM * 2);
  ushort* gw2_bf  = (ushort*)take(CDIM * CDIM * 2);
  ushort* pool_bf = (ushort*)take(NWIN * CDIM * 2);
  ushort* g1_bf   = (ushort*)take(NWIN * CDIM * 2);
  float*  g_f     = (float*)take(NWIN * CDIM * 4);
  ushort* h        = opt_ln;
  ushort* attn_out = sar_ln;
  ushort* fused    = qb;
  ushort* yb       = sar_ln;

  CvtJobs jobs;
  jobs.src[0] = wq;  jobs.dst[0] = wq_bf;               jobs.n[0] = CDIM * CDIM;
  jobs.src[1] = wk;  jobs.dst[1] = wkv_bf;              jobs.n[1] = CDIM * CDIM;
  jobs.src[2] = wv;  jobs.dst[2] = wkv_bf + CDIM * CDIM; jobs.n[2] = CDIM * CDIM;
  jobs.src[3] = wp;  jobs.dst[3] = wp_bf;               jobs.n[3] = CDIM * CDIM;
  jobs.src[4] = w1;  jobs.dst[4] = w1_bf;               jobs.n[4] = HDIM * CDIM;
  jobs.src[5] = w2;  jobs.dst[5] = w2_bf;               jobs.n[5] = CDIM * HDIM;
  jobs.src[6] = gw1; jobs.dst[6] = gw1_bf;              jobs.n[6] = CDIM * CDIM;
  jobs.src[7] = gw2; jobs.dst[7] = gw2_bf;              jobs.n[7] = CDIM * CDIM;
  cvt_kernel<<<dim3(128), dim3(256), 0, stream>>>(jobs);

  lnpart_kernel<<<dim3(NWIN), dim3(256), 0, stream>>>(
      opt, sar, lnqw, lnqb, lnkw, lnkb, opt_ln, sar_ln, opt_tok);

  gemm_kernel<EPI_BF16><<<dim3(1800, 3), dim3(256), 0, stream>>>(
      opt_ln, wq_bf, bq, bq, (void*)qb, ROWS, CDIM, CDIM, nullptr, nullptr, nullptr);
  gemm_kernel<EPI_BF16><<<dim3(1800, 6), dim3(256), 0, stream>>>(
      sar_ln, wkv_bf, bk, bv, (void*)kv, ROWS, 384, CDIM, nullptr, nullptr, nullptr);

  pool_kernel<<<dim3(NWIN), dim3(192), 0, stream>>>(sar_ln, pool_bf);
  gemm_kernel<EPI_GELU><<<dim3(13, 3), dim3(256), 0, stream>>>(
      pool_bf, gw1_bf, gb1, gb1, (void*)g1_bf, NWIN, CDIM, CDIM, nullptr, nullptr, nullptr);
  gemm_kernel<EPI_SIG><<<dim3(13, 3), dim3(256), 0, stream>>>(
      g1_bf, gw2_bf, gb2, gb2, (void*)g_f, NWIN, CDIM, CDIM, nullptr, nullptr, nullptr);

  attn_kernel<<<dim3(NWIN * 6), dim3(256), 0, stream>>>(qb, kv, attn_out);

  gemm_kernel<EPI_PROJ><<<dim3(1800, 3), dim3(256), 0, stream>>>(
      attn_out, wp_bf, bp, bp, (void*)fused, ROWS, CDIM, CDIM, g_f, opt_tok, gamma);

  lno_kernel<<<dim3(ROWS / 4), dim3(256), 0, stream>>>(fused, lnow, lnob, h);

  mlp_kernel<<<dim3(ROWS / 64), dim3(256), 0, stream>>>(h, fused, w1_bf, b1, w2_bf, b2, yb);

  unpart_kernel<<<dim3(NWIN), dim3(256), 0, stream>>>(yb, (float*)d_out);
}

// Round 6
// 1892.731 us; speedup vs baseline: 1.4631x; 1.0382x over previous
//
#include <hip/hip_runtime.h>
#include <hip/hip_bf16.h>

#define ROWS 230400   // 1600 windows * 144 tokens
#define CDIM 192
#define NTOK 144
#define NWIN 1600
#define PLANE 57600   // 240*240
#define HDIM 768

typedef __attribute__((ext_vector_type(8))) short bf16x8;
typedef __attribute__((ext_vector_type(4))) float f32x4;

__device__ __forceinline__ ushort f2bf(float f) {
  union { float f; unsigned u; } v; v.f = f;
  unsigned r = v.u + 0x7FFFu + ((v.u >> 16) & 1u);
  return (ushort)(r >> 16);
}
__device__ __forceinline__ float bf2f(ushort h) {
  union { unsigned u; float f; } v; v.u = ((unsigned)h) << 16;
  return v.f;
}
__device__ __forceinline__ float gelu_f(float x) {
  return 0.5f * x * (1.f + erff(x * 0.7071067811865475f));
}

// ---------------- weight fp32 -> bf16 ----------------
struct CvtJobs {
  const float* src[8];
  ushort* dst[8];
  int n[8];
};
__global__ __launch_bounds__(256) void cvt_kernel(CvtJobs jobs) {
  int stride = gridDim.x * blockDim.x;
  int t0 = blockIdx.x * blockDim.x + threadIdx.x;
  for (int j = 0; j < 8; ++j) {
    const float* s = jobs.src[j]; ushort* d = jobs.dst[j]; int n = jobs.n[j];
    for (int e = t0; e < n; e += stride) d[e] = f2bf(s[e]);
  }
}

// ---------------- window partition + LN (opt & sar) ----------------
__global__ __launch_bounds__(256) void lnpart_kernel(
    const float* __restrict__ opt, const float* __restrict__ sar,
    const float* __restrict__ lnqw, const float* __restrict__ lnqb,
    const float* __restrict__ lnkw, const float* __restrict__ lnkb,
    ushort* __restrict__ opt_ln, ushort* __restrict__ sar_ln,
    ushort* __restrict__ opt_tok) {
  __shared__ __align__(16) ushort X[NTOK * 200];
  __shared__ float smu[NTOK], srs[NTOK];
  int win = blockIdx.x;
  int b = win / 400, rr = win % 400, nh = rr / 20, nw = rr % 20;
  size_t wbase = (size_t)b * CDIM * PLANE + (size_t)(nh * 12) * 240 + nw * 12;
  int tid = threadIdx.x;
  for (int pass = 0; pass < 2; ++pass) {
    const float* src = pass ? sar : opt;
    for (int e = tid; e < CDIM * 36; e += 256) {
      int c = e / 36, r2 = e % 36, i = r2 / 3, j0 = (r2 % 3) * 4;
      float4 v = *(const float4*)&src[wbase + (size_t)c * PLANE + i * 240 + j0];
      int tok = i * 12 + j0;
      X[(tok + 0) * 200 + c] = f2bf(v.x);
      X[(tok + 1) * 200 + c] = f2bf(v.y);
      X[(tok + 2) * 200 + c] = f2bf(v.z);
      X[(tok + 3) * 200 + c] = f2bf(v.w);
    }
    __syncthreads();
    if (tid < NTOK) {
      float s = 0.f, qs = 0.f;
      for (int c = 0; c < CDIM; ++c) { float v = bf2f(X[tid * 200 + c]); s += v; qs += v * v; }
      float mu = s * (1.f / CDIM);
      smu[tid] = mu;
      srs[tid] = rsqrtf(qs * (1.f / CDIM) - mu * mu + 1e-5f);
    }
    __syncthreads();
    const float* w = pass ? lnkw : lnqw;
    const float* bb = pass ? lnkb : lnqb;
    ushort* dst = pass ? sar_ln : opt_ln;
    for (int e = tid; e < NTOK * CDIM; e += 256) {
      int tok = e / CDIM, c = e % CDIM;
      ushort raw = X[tok * 200 + c];
      float v = bf2f(raw);
      float y = (v - smu[tok]) * srs[tok] * w[c] + bb[c];
      size_t o = (size_t)(win * NTOK + tok) * CDIM + c;
      dst[o] = f2bf(y);
      if (!pass) opt_tok[o] = raw;
    }
    __syncthreads();
  }
}

// ---------------- generic bf16 MFMA GEMM: out = epi(A @ W^T + bias) ----------------
// A: [M][K] bf16 row-major; W: [N][K] bf16 ('oi' layout, k contiguous)
enum { EPI_BF16 = 0, EPI_GELU = 1, EPI_SIG = 2, EPI_PROJ = 3 };

template <int EPI>
__global__ __launch_bounds__(256) void gemm_kernel(
    const ushort* __restrict__ A, const ushort* __restrict__ Wt,
    const float* __restrict__ bias, const float* __restrict__ bias2,
    void* __restrict__ outp, int M, int N, int K,
    const float* __restrict__ g, const ushort* __restrict__ opt_tok,
    const float* __restrict__ gamma_p) {
  __shared__ __align__(16) ushort Alds[128 * 40];  // +8 pad breaks bank aliasing
  int m0 = blockIdx.x * 128;
  int n0 = blockIdx.y * 64;
  int tid = threadIdx.x;
  int wave = tid >> 6, lane = tid & 63, ls = lane & 15, quad = lane >> 4;
  f32x4 acc[2][4] = {};
  for (int k0 = 0; k0 < K; k0 += 32) {
    for (int it = 0; it < 2; ++it) {
      int ch = tid + 256 * it;
      int r = ch >> 2, c8 = (ch & 3) * 8;
      int grow = m0 + r; if (grow > M - 1) grow = M - 1;
      *(bf16x8*)&Alds[r * 40 + c8] = *(const bf16x8*)&A[(size_t)grow * K + k0 + c8];
    }
    __syncthreads();
    int mb = wave * 32;
    bf16x8 af0 = *(const bf16x8*)&Alds[(mb + ls) * 40 + quad * 8];
    bf16x8 af1 = *(const bf16x8*)&Alds[(mb + 16 + ls) * 40 + quad * 8];
    bf16x8 bfr[4];
    for (int nf = 0; nf < 4; ++nf)
      bfr[nf] = *(const bf16x8*)&Wt[(size_t)(n0 + nf * 16 + ls) * K + k0 + quad * 8];
    for (int nf = 0; nf < 4; ++nf) {
      acc[0][nf] = __builtin_amdgcn_mfma_f32_16x16x32_bf16(af0, bfr[nf], acc[0][nf], 0, 0, 0);
      acc[1][nf] = __builtin_amdgcn_mfma_f32_16x16x32_bf16(af1, bfr[nf], acc[1][nf], 0, 0, 0);
    }
    __syncthreads();
  }
  float gam = (EPI == EPI_PROJ) ? gamma_p[0] : 0.f;
  for (int s = 0; s < 2; ++s) {
    int rowbase = m0 + wave * 32 + s * 16 + quad * 4;
    for (int nf = 0; nf < 4; ++nf) {
      int col = n0 + nf * 16 + ls;
      float bb = (col < 192) ? bias[col] : bias2[col - 192];
      for (int r = 0; r < 4; ++r) {
        int row = rowbase + r;
        if (row >= M) continue;
        float v = acc[s][nf][r] + bb;
        if (EPI == EPI_BF16) {
          ((ushort*)outp)[(size_t)row * N + col] = f2bf(v);
        } else if (EPI == EPI_GELU) {
          ((ushort*)outp)[(size_t)row * N + col] = f2bf(gelu_f(v));
        } else if (EPI == EPI_SIG) {
          ((float*)outp)[(size_t)row * N + col] = 1.f / (1.f + __expf(-v));
        } else {  // EPI_PROJ: fused = opt_tok + gamma * g * (proj)
          int win = row / NTOK;
          float gv = g[(size_t)win * CDIM + col];
          float ov = bf2f(opt_tok[(size_t)row * CDIM + col]);
          ((ushort*)outp)[(size_t)row * CDIM + col] = f2bf(ov + gam * gv * v);
        }
      }
    }
  }
}

// ---------------- per-window token-mean of sar_ln ----------------
__global__ __launch_bounds__(192) void pool_kernel(const ushort* __restrict__ sar_ln,
                                                   ushort* __restrict__ pool) {
  int win = blockIdx.x, c = threadIdx.x;
  float s = 0.f;
  size_t base = (size_t)win * NTOK * CDIM + c;
  for (int t = 0; t < NTOK; ++t) s += bf2f(sar_ln[base + (size_t)t * CDIM]);
  pool[(size_t)win * CDIM + c] = f2bf(s * (1.f / NTOK));
}

// ---------------- attention: one block per (window, head) ----------------
__global__ __launch_bounds__(256) void attn_kernel(const ushort* __restrict__ q,
                                                   const ushort* __restrict__ kv,
                                                   ushort* __restrict__ attn_out) {
  __shared__ __align__(16) ushort vT[32 * 168];     // v transposed, K zero-padded to 160
  __shared__ __align__(16) ushort P[4][16 * 168];   // per-wave P tile (A-layout source)
  int blk = blockIdx.x;
  int win = blk / 6, head = blk % 6;
  int tid = threadIdx.x, wave = tid >> 6, lane = tid & 63, ls = lane & 15, quad = lane >> 4;
  size_t qbase = (size_t)win * NTOK * CDIM + head * 32;
  size_t kbase = (size_t)win * NTOK * 384 + head * 32;
  size_t vbase = kbase + 192;
  for (int e = tid; e < NTOK * 32; e += 256) {
    int t = e >> 5, d = e & 31;
    vT[d * 168 + t] = kv[vbase + (size_t)t * 384 + d];
  }
  for (int e = tid; e < 32 * 24; e += 256) {
    int d = e / 24, j = 144 + e % 24;
    vT[d * 168 + j] = 0;
  }
  __syncthreads();
  const float scale = 0.17677669529663687f;  // 32^-0.5
  ushort* Pw = P[wave];
  f32x4 zero = {0.f, 0.f, 0.f, 0.f};
  for (int mt = wave; mt < 9; mt += 4) {
    int m0 = mt * 16;
    bf16x8 aq = *(const bf16x8*)&q[qbase + (size_t)(m0 + ls) * CDIM + quad * 8];
    f32x4 S[9];
    for (int nt = 0; nt < 9; ++nt) {
      bf16x8 bk = *(const bf16x8*)&kv[kbase + (size_t)(nt * 16 + ls) * 384 + quad * 8];
      S[nt] = __builtin_amdgcn_mfma_f32_16x16x32_bf16(aq, bk, zero, 0, 0, 0);
    }
    for (int nt = 0; nt < 9; ++nt)
      for (int r = 0; r < 4; ++r) S[nt][r] *= scale;
    // softmax per row (row = quad*4+r lives in reg r of the 16 lanes sharing `quad`)
    for (int r = 0; r < 4; ++r) {
      float mx = -1e30f;
      for (int nt = 0; nt < 9; ++nt) mx = fmaxf(mx, S[nt][r]);
      for (int o = 1; o < 16; o <<= 1) mx = fmaxf(mx, __shfl_xor(mx, o));
      float sm = 0.f;
      for (int nt = 0; nt < 9; ++nt) { float e = __expf(S[nt][r] - mx); S[nt][r] = e; sm += e; }
      for (int o = 1; o < 16; o <<= 1) sm += __shfl_xor(sm, o);
      float inv = 1.f / sm;
      for (int nt = 0; nt < 9; ++nt)
        Pw[(quad * 4 + r) * 168 + nt * 16 + ls] = f2bf(S[nt][r] * inv);
    }
    for (int e = lane; e < 16 * 24; e += 64) {  // zero K-pad cols 144..167
      int r = e / 24, j = 144 + e % 24;
      Pw[r * 168 + j] = 0;
    }
    f32x4 O[2] = {};
    for (int ks = 0; ks < 5; ++ks) {
      bf16x8 ap = *(const bf16x8*)&Pw[ls * 168 + ks * 32 + quad * 8];
      for (int dt = 0; dt < 2; ++dt) {
        bf16x8 bv = *(const bf16x8*)&vT[(dt * 16 + ls) * 168 + ks * 32 + quad * 8];
        O[dt] = __builtin_amdgcn_mfma_f32_16x16x32_bf16(ap, bv, O[dt], 0, 0, 0);
      }
    }
    for (int dt = 0; dt < 2; ++dt)
      for (int r = 0; r < 4; ++r)
        attn_out[(size_t)(win * NTOK + m0 + quad * 4 + r) * CDIM + head * 32 + dt * 16 + ls] =
            f2bf(O[dt][r]);
  }
}

// ---------------- fused LN + MLP: y = fused + gelu(LN(fused)@w1^T+b1)@w2^T + b2 --------
// R5 confirmed the LDS-staged-weights theory (1205->405 us). Remaining exposed
// latency: the global weight load sits between the two staging barriers. Fix:
// async-stage split (T14) -- registers rw1/rw2 hold chunk c+1's weights, loaded
// during chunk c's compute; the barrier pair now only covers ds_writes.
// Also fused: the output LayerNorm (former lno_kernel). afrag rows are
// lane-local (row = wrow+ls, 48 cols/lane across quads); mean/var via
// __shfl_xor(16|32) over the 4 quads. Kills an 88.5MB write + 88.5MB read.
// LDS 33.3K -> 4 blocks/CU tier -> 128-VGPR budget (R5-validated).
// Persistent regs: afrag 24 + acc 48 + rw 24 = 96; watch WRITE_SIZE canary.
__global__ __launch_bounds__(256) void mlp_kernel(
    const ushort* __restrict__ fused,
    const float* __restrict__ lnow, const float* __restrict__ lnob,
    const ushort* __restrict__ w1b, const float* __restrict__ b1,
    const ushort* __restrict__ w2b, const float* __restrict__ b2,
    ushort* __restrict__ y) {
  __shared__ __align__(16) ushort W1s[32 * 200];  // w1 chunk [32 hid][192 k], pad->200
  __shared__ __align__(16) ushort W2s[192 * 40];  // w2 chunk [192 out][32 k], pad->40
  __shared__ __align__(16) ushort Ts[64 * 40];    // gelu(t) [64 rows][32 k], pad->40
  int m0 = blockIdx.x * 64;
  int tid = threadIdx.x, wave = tid >> 6, lane = tid & 63, ls = lane & 15, quad = lane >> 4;
  int wrow = wave * 16;
  // prologue: load chunk 0 weight slices into staging regs
  bf16x8 rw1[3], rw2[3];
#pragma unroll
  for (int it = 0; it < 3; ++it) {
    int ch = tid + 256 * it;
    rw1[it] = *(const bf16x8*)&w1b[(size_t)(ch / 24) * CDIM + (ch % 24) * 8];
    rw2[it] = *(const bf16x8*)&w2b[(size_t)(ch / 4) * HDIM + (ch % 4) * 8];
  }
  // load raw fused rows; compute LN in-register (fused lno)
  bf16x8 afrag[6];
#pragma unroll
  for (int ks = 0; ks < 6; ++ks)
    afrag[ks] = *(const bf16x8*)&fused[(size_t)(m0 + wrow + ls) * CDIM + ks * 32 + quad * 8];
  {
    float s = 0.f, qs = 0.f;
#pragma unroll
    for (int ks = 0; ks < 6; ++ks)
#pragma unroll
      for (int j = 0; j < 8; ++j) {
        float v = bf2f((ushort)afrag[ks][j]);
        s += v; qs += v * v;
      }
    s += __shfl_xor(s, 16); s += __shfl_xor(s, 32);
    qs += __shfl_xor(qs, 16); qs += __shfl_xor(qs, 32);
    float mu = s * (1.f / CDIM);
    float rs = rsqrtf(qs * (1.f / CDIM) - mu * mu + 1e-5f);
#pragma unroll
    for (int ks = 0; ks < 6; ++ks)
#pragma unroll
      for (int j = 0; j < 8; ++j) {
        int c = ks * 32 + quad * 8 + j;
        float v = (bf2f((ushort)afrag[ks][j]) - mu) * rs * lnow[c] + lnob[c];
        afrag[ks][j] = (short)f2bf(v);
      }
  }
  f32x4 acc[12] = {};
  for (int hc = 0; hc < HDIM; hc += 32) {
    __syncthreads();  // all waves done reading previous chunk's W1s/W2s
#pragma unroll
    for (int it = 0; it < 3; ++it) {
      int ch = tid + 256 * it;
      *(bf16x8*)&W1s[(ch / 24) * 200 + (ch % 24) * 8] = rw1[it];
      *(bf16x8*)&W2s[(ch / 4) * 40 + (ch % 4) * 8] = rw2[it];
    }
    __syncthreads();  // chunk staged
    // issue next chunk's loads; latency hides under this chunk's compute
    if (hc + 32 < HDIM) {
      int hn = hc + 32;
#pragma unroll
      for (int it = 0; it < 3; ++it) {
        int ch = tid + 256 * it;
        rw1[it] = *(const bf16x8*)&w1b[(size_t)(hn + ch / 24) * CDIM + (ch % 24) * 8];
        rw2[it] = *(const bf16x8*)&w2b[(size_t)(ch / 4) * HDIM + hn + (ch % 4) * 8];
      }
    }
    // GEMM1: 16 rows x 32 hidden cols, K=192
    f32x4 t[2] = {};
#pragma unroll
    for (int ks = 0; ks < 6; ++ks) {
#pragma unroll
      for (int nf = 0; nf < 2; ++nf) {
        bf16x8 bw = *(const bf16x8*)&W1s[(nf * 16 + ls) * 200 + ks * 32 + quad * 8];
        t[nf] = __builtin_amdgcn_mfma_f32_16x16x32_bf16(afrag[ks], bw, t[nf], 0, 0, 0);
      }
    }
    // bias + gelu -> Ts (wave-private rows; same-wave write->read via lgkmcnt)
#pragma unroll
    for (int nf = 0; nf < 2; ++nf) {
      float bb = b1[hc + nf * 16 + ls];
#pragma unroll
      for (int r = 0; r < 4; ++r) {
        float v = gelu_f(t[nf][r] + bb);
        Ts[(wrow + quad * 4 + r) * 40 + nf * 16 + ls] = f2bf(v);
      }
    }
    // GEMM2: 16 rows x 192 out cols, K=32 (this chunk), accumulate
    bf16x8 ap = *(const bf16x8*)&Ts[(wrow + ls) * 40 + quad * 8];
#pragma unroll
    for (int nf = 0; nf < 12; ++nf) {
      bf16x8 bw = *(const bf16x8*)&W2s[(nf * 16 + ls) * 40 + quad * 8];
      acc[nf] = __builtin_amdgcn_mfma_f32_16x16x32_bf16(ap, bw, acc[nf], 0, 0, 0);
    }
  }
#pragma unroll
  for (int nf = 0; nf < 12; ++nf) {
    float bb = b2[nf * 16 + ls];
#pragma unroll
    for (int r = 0; r < 4; ++r) {
      size_t idx = (size_t)(m0 + wrow + quad * 4 + r) * CDIM + nf * 16 + ls;
      y[idx] = f2bf(bf2f(fused[idx]) + acc[nf][r] + bb);
    }
  }
}

// ---------------- window reverse -> [B,C,H,W] fp32 ----------------
__global__ __launch_bounds__(256) void unpart_kernel(const ushort* __restrict__ y,
                                                     float* __restrict__ out) {
  __shared__ __align__(16) ushort X[NTOK * 200];
  int win = blockIdx.x;
  int b = win / 400, rr = win % 400, nh = rr / 20, nw = rr % 20;
  size_t wbase = (size_t)b * CDIM * PLANE + (size_t)(nh * 12) * 240 + nw * 12;
  int tid = threadIdx.x;
  for (int e = tid; e < NTOK * 24; e += 256) {
    int tok = e / 24, c8 = (e % 24) * 8;
    *(bf16x8*)&X[tok * 200 + c8] = *(const bf16x8*)&y[(size_t)(win * NTOK + tok) * CDIM + c8];
  }
  __syncthreads();
  for (int e = tid; e < CDIM * 36; e += 256) {
    int c = e / 36, r2 = e % 36, i = r2 / 3, j0 = (r2 % 3) * 4;
    int tok = i * 12 + j0;
    float4 v;
    v.x = bf2f(X[(tok + 0) * 200 + c]);
    v.y = bf2f(X[(tok + 1) * 200 + c]);
    v.z = bf2f(X[(tok + 2) * 200 + c]);
    v.w = bf2f(X[(tok + 3) * 200 + c]);
    *(float4*)&out[wbase + (size_t)c * PLANE + i * 240 + j0] = v;
  }
}

extern "C" void kernel_launch(void* const* d_in, const int* in_sizes, int n_in,
                              void* d_out, int out_size, void* d_ws, size_t ws_size,
                              hipStream_t stream) {
  const float* opt   = (const float*)d_in[0];
  const float* sar   = (const float*)d_in[1];
  const float* lnqw  = (const float*)d_in[2];
  const float* lnqb  = (const float*)d_in[3];
  const float* lnkw  = (const float*)d_in[4];
  const float* lnkb  = (const float*)d_in[5];
  const float* wq    = (const float*)d_in[6];
  const float* bq    = (const float*)d_in[7];
  const float* wk    = (const float*)d_in[8];
  const float* bk    = (const float*)d_in[9];
  const float* wv    = (const float*)d_in[10];
  const float* bv    = (const float*)d_in[11];
  const float* wp    = (const float*)d_in[12];
  const float* bp    = (const float*)d_in[13];
  const float* gw1   = (const float*)d_in[14];
  const float* gb1   = (const float*)d_in[15];
  const float* gw2   = (const float*)d_in[16];
  const float* gb2   = (const float*)d_in[17];
  const float* gamma = (const float*)d_in[18];
  const float* lnow  = (const float*)d_in[19];
  const float* lnob  = (const float*)d_in[20];
  const float* w1    = (const float*)d_in[21];
  const float* b1    = (const float*)d_in[22];
  const float* w2    = (const float*)d_in[23];
  const float* b2    = (const float*)d_in[24];

  char* ws = (char*)d_ws;
  size_t off = 0;
  auto take = [&](size_t bytes) -> char* {
    char* p = ws + off;
    off += (bytes + 255) & ~(size_t)255;
    return p;
  };
  const size_t big = (size_t)ROWS * CDIM * 2;  // 88.5 MB
  ushort* opt_ln  = (ushort*)take(big);
  ushort* sar_ln  = (ushort*)take(big);                 // -> attn_out -> y
  ushort* opt_tok = (ushort*)take(big);
  ushort* qb      = (ushort*)take(big);                 // -> fused
  ushort* kv      = (ushort*)take((size_t)ROWS * 384 * 2);
  ushort* wq_bf   = (ushort*)take(CDIM * CDIM * 2);
  ushort* wkv_bf  = (ushort*)take(2 * CDIM * CDIM * 2);
  ushort* wp_bf   = (ushort*)take(CDIM * CDIM * 2);
  ushort* w1_bf   = (ushort*)take((size_t)HDIM * CDIM * 2);
  ushort* w2_bf   = (ushort*)take((size_t)CDIM * HDIM * 2);
  ushort* gw1_bf  = (ushort*)take(CDIM * CDIM * 2);
  ushort* gw2_bf  = (ushort*)take(CDIM * CDIM * 2);
  ushort* pool_bf = (ushort*)take(NWIN * CDIM * 2);
  ushort* g1_bf   = (ushort*)take(NWIN * CDIM * 2);
  float*  g_f     = (float*)take(NWIN * CDIM * 4);
  ushort* attn_out = sar_ln;
  ushort* fused    = qb;
  ushort* yb       = sar_ln;

  CvtJobs jobs;
  jobs.src[0] = wq;  jobs.dst[0] = wq_bf;               jobs.n[0] = CDIM * CDIM;
  jobs.src[1] = wk;  jobs.dst[1] = wkv_bf;              jobs.n[1] = CDIM * CDIM;
  jobs.src[2] = wv;  jobs.dst[2] = wkv_bf + CDIM * CDIM; jobs.n[2] = CDIM * CDIM;
  jobs.src[3] = wp;  jobs.dst[3] = wp_bf;               jobs.n[3] = CDIM * CDIM;
  jobs.src[4] = w1;  jobs.dst[4] = w1_bf;               jobs.n[4] = HDIM * CDIM;
  jobs.src[5] = w2;  jobs.dst[5] = w2_bf;               jobs.n[5] = CDIM * HDIM;
  jobs.src[6] = gw1; jobs.dst[6] = gw1_bf;              jobs.n[6] = CDIM * CDIM;
  jobs.src[7] = gw2; jobs.dst[7] = gw2_bf;              jobs.n[7] = CDIM * CDIM;
  cvt_kernel<<<dim3(128), dim3(256), 0, stream>>>(jobs);

  lnpart_kernel<<<dim3(NWIN), dim3(256), 0, stream>>>(
      opt, sar, lnqw, lnqb, lnkw, lnkb, opt_ln, sar_ln, opt_tok);

  gemm_kernel<EPI_BF16><<<dim3(1800, 3), dim3(256), 0, stream>>>(
      opt_ln, wq_bf, bq, bq, (void*)qb, ROWS, CDIM, CDIM, nullptr, nullptr, nullptr);
  gemm_kernel<EPI_BF16><<<dim3(1800, 6), dim3(256), 0, stream>>>(
      sar_ln, wkv_bf, bk, bv, (void*)kv, ROWS, 384, CDIM, nullptr, nullptr, nullptr);

  pool_kernel<<<dim3(NWIN), dim3(192), 0, stream>>>(sar_ln, pool_bf);
  gemm_kernel<EPI_GELU><<<dim3(13, 3), dim3(256), 0, stream>>>(
      pool_bf, gw1_bf, gb1, gb1, (void*)g1_bf, NWIN, CDIM, CDIM, nullptr, nullptr, nullptr);
  gemm_kernel<EPI_SIG><<<dim3(13, 3), dim3(256), 0, stream>>>(
      g1_bf, gw2_bf, gb2, gb2, (void*)g_f, NWIN, CDIM, CDIM, nullptr, nullptr, nullptr);

  attn_kernel<<<dim3(NWIN * 6), dim3(256), 0, stream>>>(qb, kv, attn_out);

  gemm_kernel<EPI_PROJ><<<dim3(1800, 3), dim3(256), 0, stream>>>(
      attn_out, wp_bf, bp, bp, (void*)fused, ROWS, CDIM, CDIM, g_f, opt_tok, gamma);

  mlp_kernel<<<dim3(ROWS / 64), dim3(256), 0, stream>>>(
      fused, lnow, lnob, w1_bf, b1, w2_bf, b2, yb);

  unpart_kernel<<<dim3(NWIN), dim3(256), 0, stream>>>(yb, (float*)d_out);
}